// Round 5
// baseline (770.899 us; speedup 1.0000x reference)
//
#include <hip/hip_runtime.h>

#define BB 128
#define TT 1024
#define HH 512
#define KK 50

__device__ __forceinline__ float rl_f(float x, int lane) {
    return __int_as_float(__builtin_amdgcn_readlane(__float_as_int(x), lane));
}

// Opaque register barrier: forces values to be VGPR-resident at this point.
#define PIN10(A,B) asm volatile("" : "+v"(A[B+0]),"+v"(A[B+1]),"+v"(A[B+2]), \
    "+v"(A[B+3]),"+v"(A[B+4]),"+v"(A[B+5]),"+v"(A[B+6]),"+v"(A[B+7]), \
    "+v"(A[B+8]),"+v"(A[B+9]))
#define PIN50(A) do { PIN10(A,0); PIN10(A,10); PIN10(A,20); PIN10(A,30); PIN10(A,40); } while (0)

// Wave-wide max via DPP (VALU latency, no LDS). old=self + bound_ctrl=false:
// invalid lanes keep their own value -> result is always a max over a SUBSET
// of real candidate values (never a fabricated 0), so a semantic surprise can
// only loosen the bound, never corrupt it. ctrl must be an ICE -> template.
template <int CTRL>
__device__ __forceinline__ float dppmax(float x) {
    int xi = __float_as_int(x);
    int yi = __builtin_amdgcn_update_dpp(xi, xi, CTRL, 0xf, 0xf, false);
    return fmaxf(x, __int_as_float(yi));
}

// ---------------------------------------------------------------------------
// Kernel 1: feats[bt][k] = sum_h hidden[bt][h] * W[k][h] + b[k]   (unchanged)
// ---------------------------------------------------------------------------
__global__ __launch_bounds__(256, 4) void gemm_feats(
    const float* __restrict__ hidden, const float* __restrict__ W,
    const float* __restrict__ bias, float* __restrict__ feats)
{
    __shared__ float At[32][132];
    __shared__ float Wt[32][68];
    const int tid = threadIdx.x;
    const int ri  = tid & 31;
    const int ki  = tid >> 5;
    const long row0 = (long)blockIdx.x * 128;

    float acc[4][8];
    #pragma unroll
    for (int r = 0; r < 4; ++r)
        #pragma unroll
        for (int k = 0; k < 8; ++k) acc[r][k] = 0.f;

    for (int h0 = 0; h0 < HH; h0 += 32) {
        #pragma unroll
        for (int it = 0; it < 4; ++it) {
            int idx = tid + 256 * it;
            int r = idx >> 3, hq = idx & 7;
            float4 a = *(const float4*)(hidden + (row0 + r) * HH + h0 + hq * 4);
            At[hq*4+0][r] = a.x; At[hq*4+1][r] = a.y;
            At[hq*4+2][r] = a.z; At[hq*4+3][r] = a.w;
        }
        #pragma unroll
        for (int it = 0; it < 2; ++it) {
            int idx = tid + 256 * it;
            int k = idx >> 3, hq = idx & 7;
            float4 w = make_float4(0.f, 0.f, 0.f, 0.f);
            if (k < KK) w = *(const float4*)(W + k * HH + h0 + hq * 4);
            Wt[hq*4+0][k] = w.x; Wt[hq*4+1][k] = w.y;
            Wt[hq*4+2][k] = w.z; Wt[hq*4+3][k] = w.w;
        }
        __syncthreads();
        #pragma unroll
        for (int h = 0; h < 32; ++h) {
            float a[4], w[8];
            *(float4*)a     = *(const float4*)&At[h][ri * 4];
            *(float4*)w     = *(const float4*)&Wt[h][ki * 8];
            *(float4*)(w+4) = *(const float4*)&Wt[h][ki * 8 + 4];
            #pragma unroll
            for (int r = 0; r < 4; ++r)
                #pragma unroll
                for (int k = 0; k < 8; ++k)
                    acc[r][k] += a[r] * w[k];
        }
        __syncthreads();
    }
    #pragma unroll
    for (int r = 0; r < 4; ++r) {
        long row = row0 + ri * 4 + r;
        #pragma unroll
        for (int k = 0; k < 8; ++k) {
            int kg = ki * 8 + k;
            if (kg < KK) feats[row * KK + kg] = acc[r][k] + bias[kg];
        }
    }
}

// ---------------------------------------------------------------------------
// Kernel 2: single-wave Viterbi forward with EXACT candidate pruning.
//   lb = max_i(v_i + rmin_i)  is a lower bound on every m_j;
//   any i with v_i + rmax_i < lb can never achieve the max for any j.
// Typical survivor count with this data: 1-3 of 50  ->  per-step work drops
// from ~155 VALU to ~35 instr + one LDS-read latency. Values are bit-exact
// (max over a superset-of-winners subset == full max).
// ---------------------------------------------------------------------------
__global__ __launch_bounds__(64, 1) void viterbi_fwd(
    float* __restrict__ fv, const float* __restrict__ trans,
    const float* __restrict__ startT, const float* __restrict__ stopT,
    float* __restrict__ out_score, int* __restrict__ lastTag)
{
    __shared__ float Tl[KK][64];     // Tl[i][j] = trans[i][j]; 64-stride cols

    const int b  = blockIdx.x;
    const int j  = threadIdx.x;
    const int jc = j < KK ? j : KK - 1;

    // Stage T into LDS (lane j owns column j).
    if (j < KK) {
        #pragma unroll
        for (int i = 0; i < KK; ++i) Tl[i][j] = trans[i * KK + j];
    }
    // Row stats: lane l is candidate l (clamped). One-time, unrolled loads.
    float rmax = -1e30f, rmin = 1e30f;
    #pragma unroll
    for (int q = 0; q < KK; ++q) {
        float tv = trans[jc * KK + q];
        rmax = fmaxf(rmax, tv);
        rmin = fminf(rmin, tv);
    }
    __syncthreads();

    float* p = fv + (size_t)b * TT * KK;
    float v  = p[jc] + startT[jc];
    p[jc] = v;
    float f1 = p[KK + jc];
    float f2 = p[2 * KK + jc];
    float f3 = p[3 * KK + jc];
    float f4 = p[4 * KK + jc];

    const unsigned long long lanemask = (1ull << KK) - 1;

    #pragma unroll 1
    for (int t = 1; t < TT; ++t) {
        float f = f1; f1 = f2; f2 = f3; f3 = f4;
        if (t + 4 < TT) f4 = p[(size_t)(t + 4) * KK + jc];

        // ---- prune mask ----
        float r = v + rmin;
        r = dppmax<0x111>(r);        // row_shr:1
        r = dppmax<0x112>(r);        // row_shr:2
        r = dppmax<0x114>(r);        // row_shr:4
        r = dppmax<0x118>(r);        // row_shr:8
        r = dppmax<0x142>(r);        // row_bcast:15
        r = dppmax<0x143>(r);        // row_bcast:31  -> lane 63 = full max
        float lb = rl_f(r, 63);

        unsigned long long mask = __ballot(v + rmax >= lb) & lanemask;
        if (mask == 0ull) mask = lanemask;   // paranoia: never drop candidates

        // ---- survivors (common case: 1-2) ----
        int i0 = __builtin_ctzll(mask);
        unsigned long long m2 = mask & (mask - 1);
        int i1 = m2 ? __builtin_ctzll(m2) : i0;
        unsigned long long rest = m2 ? (m2 & (m2 - 1)) : 0ull;

        float t0 = Tl[i0][jc];
        float t1 = Tl[i1][jc];
        float x0 = rl_f(v, i0) + t0;
        float x1 = rl_f(v, i1) + t1;
        float m  = fmaxf(x0, x1);

        while (rest) {                        // rare
            int ii = __builtin_ctzll(rest); rest &= rest - 1;
            m = fmaxf(m, rl_f(v, ii) + Tl[ii][jc]);
        }

        v = f + m;
        p[(size_t)t * KK + jc] = v;
    }

    v += stopT[jc];
    float bestv = rl_f(v, 0); int besti = 0;
    #pragma unroll
    for (int i = 1; i < KK; ++i) {
        float xx = rl_f(v, i);
        if (xx > bestv) { bestv = xx; besti = i; }
    }
    if (j == 0) { out_score[b] = bestv; lastTag[b] = besti; }
}

// ---------------------------------------------------------------------------
// Kernel 3a: recompute backpointers per 32-step chunk + chunk maps. (unchanged)
// ---------------------------------------------------------------------------
__global__ __launch_bounds__(64, 4) void bt_maps(
    const float* __restrict__ v, const float* __restrict__ trans,
    unsigned char* __restrict__ bp, int* __restrict__ M)
{
    const int b = blockIdx.x, c = blockIdx.y;
    const int j = threadIdx.x;
    const int jc = j < KK ? j : KK - 1;

    float tc[KK];
    #pragma unroll
    for (int i = 0; i < KK; ++i) tc[i] = trans[i * KK + jc];
    PIN50(tc);

    const float* vb = v + (size_t)b * TT * KK;
    const int lo = c * 32;
    const int hi = min(c * 32 + 31, TT - 2);

    int cur = jc;
    float vnext = vb[(size_t)hi * KK + jc];

    #pragma unroll 1
    for (int s = hi; s >= lo; --s) {
        float vl = vnext;
        if (s > lo) vnext = vb[(size_t)(s - 1) * KK + jc];

        float best = rl_f(vl, 0) + tc[0];
        int   bi   = 0;
        #pragma unroll
        for (int i = 1; i < KK; ++i) {
            float cand = rl_f(vl, i) + tc[i];
            bool g = cand > best;            // strict: first index wins ties
            best = g ? cand : best;
            bi   = g ? i : bi;
        }

        if (j < KK)
            bp[((size_t)s * BB + b) * KK + j] = (unsigned char)bi;

        cur = __shfl(bi, cur, 64);           // compose: cur = bp_s[cur]
    }

    if (j < KK) M[(b * 32 + c) * KK + j] = cur;
}

// ---------------------------------------------------------------------------
// Kernel 3b: compose boundary tags serially, then 32 lanes re-walk chunks.
// ---------------------------------------------------------------------------
__global__ void bt_emit(const unsigned char* __restrict__ bp,
                        const int* __restrict__ M,
                        const int* __restrict__ lastTag,
                        float* __restrict__ tags)
{
    __shared__ int Ml[32][KK];
    __shared__ int e[33];
    const int b = blockIdx.x, tid = threadIdx.x;

    for (int i = tid; i < 32 * KK; i += 64)
        Ml[i / KK][i % KK] = M[b * 32 * KK + i];
    __syncthreads();

    if (tid == 0) {
        int cur = lastTag[b];
        e[32] = cur;
        for (int c = 31; c >= 0; --c) { cur = Ml[c][cur]; e[c] = cur; }
    }
    __syncthreads();

    if (tid < 32) {
        const int c  = tid;
        const int lo = c * 32;
        const int hi = min(c * 32 + 31, TT - 2);
        int cur = e[c + 1];
        for (int k = hi; k >= lo; --k) {
            cur = bp[((size_t)k * BB + b) * KK + cur];
            tags[(size_t)b * TT + k] = (float)cur;
        }
    }
    if (tid == 32) tags[(size_t)b * TT + (TT - 1)] = (float)lastTag[b];
}

// ---------------------------------------------------------------------------
extern "C" void kernel_launch(void* const* d_in, const int* in_sizes, int n_in,
                              void* d_out, int out_size, void* d_ws, size_t ws_size,
                              hipStream_t stream)
{
    const float* hidden = (const float*)d_in[0];
    const float* W      = (const float*)d_in[1];
    const float* bias   = (const float*)d_in[2];
    const float* trans  = (const float*)d_in[3];
    const float* startT = (const float*)d_in[4];
    const float* stopT  = (const float*)d_in[5];

    float* out = (float*)d_out;           // [0:128] best_score, [128:] tags

    char* ws = (char*)d_ws;
    float*         fv    = (float*)ws;                               // feats -> v in place
    unsigned char* bp    = (unsigned char*)(ws + 26214400);
    int*           M     = (int*)(ws + 32761600);
    int*           lastT = (int*)(ws + 33580800);

    gemm_feats<<<dim3((BB * TT) / 128), 256, 0, stream>>>(hidden, W, bias, fv);
    viterbi_fwd<<<dim3(BB), 64, 0, stream>>>(fv, trans, startT, stopT, out, lastT);
    bt_maps<<<dim3(BB, 32), 64, 0, stream>>>(fv, trans, bp, M);
    bt_emit<<<dim3(BB), 64, 0, stream>>>(bp, M, lastT, out + BB);
}